// Round 4
// baseline (1433.188 us; speedup 1.0000x reference)
//
#include <hip/hip_runtime.h>

#define NUM_USERS 80000
#define NUM_ITEMS 40000
#define NUM_NODES 120000
#define DIM 64
#define ALPHA_C 0.8f

typedef unsigned short u16;
typedef unsigned int u32;
typedef int   i2v __attribute__((ext_vector_type(2)));
typedef u32   u4v __attribute__((ext_vector_type(4)));
typedef float f4v __attribute__((ext_vector_type(4)));

// fp32 -> bf16 round-nearest-even
__device__ __forceinline__ u16 f2bf(float f) {
    union { float f; u32 i; } v;
    v.f = f;
    u32 i = v.i;
    u32 r = (i + 0x7FFFu + ((i >> 16) & 1u)) >> 16;
    return (u16)r;
}
__device__ __forceinline__ float lo_bf(u32 u) { return __uint_as_float(u << 16); }
__device__ __forceinline__ float hi_bf(u32 u) { return __uint_as_float(u & 0xffff0000u); }

// accumulate 8 bf16 (packed in uint4) * v into acc[8]
__device__ __forceinline__ void acc8(float* __restrict__ acc, float v, uint4 q) {
    const u32* p = (const u32*)&q;
#pragma unroll
    for (int k = 0; k < 4; ++k) {
        u32 u = p[k];
        acc[2 * k]     = fmaf(v, lo_bf(u), acc[2 * k]);
        acc[2 * k + 1] = fmaf(v, hi_bf(u), acc[2 * k + 1]);
    }
}

__device__ __forceinline__ uint4 ldrow(const u16* __restrict__ x, int c, int li) {
    return *((const uint4*)(x + (size_t)c * DIM) + li);
}

// ---------------------------------------------------------------------------
// Depth-4 software-pipelined segment gather over a PACKED {col,val} stream.
// 8-lane group walks its segment. Per iteration: load edge-pair p, issue
// row gathers for pair p-2, consume pair p-4.
// NOTE (R2 lesson): edge loads MUST be normal cached loads, not nontemporal.
// The group walks the stream sequentially, so each 64B line is touched 4x;
// nt evict-first re-fetched every touch -> +82 MB FETCH, +33% time.
// R4: rows are degree-sorted by the caller so the 8 groups of a wave have
// near-equal n -> the EXEC-masked max(n)-makespan waste (~24%) collapses.
// Per-row arithmetic and order unchanged -> outputs bitwise identical.
// ---------------------------------------------------------------------------
template <bool SUMV>
__device__ __forceinline__ void seg_pipe(const i2v* __restrict__ ep0,
                                         int start, int end,
                                         const u16* __restrict__ x,
                                         int li,
                                         float* __restrict__ acc,
                                         float* __restrict__ vsum) {
    const int n = end - start;
    const i2v* ep = ep0 + start;
    float s = 0.f;
    const int np = n >> 1;
    if (np >= 4) {
        i2v ea0 = ep[0], ea1 = ep[1];
        i2v eb0 = ep[2], eb1 = ep[3];
        i2v ec0 = ep[4], ec1 = ep[5];
        i2v ed0 = ep[6], ed1 = ep[7];
        uint4 xa0 = ldrow(x, ea0.x, li), xa1 = ldrow(x, ea1.x, li);
        uint4 xb0 = ldrow(x, eb0.x, li), xb1 = ldrow(x, eb1.x, li);
        for (int p = 4; p < np; ++p) {
            // E: prefetch edge pair p (2 iterations ahead of its gather)
            i2v ee0 = ep[2 * p];
            i2v ee1 = ep[2 * p + 1];
            // G: issue row gathers for pair p-2 (edges arrived long ago)
            uint4 xc0 = ldrow(x, ec0.x, li);
            uint4 xc1 = ldrow(x, ec1.x, li);
            // C: consume pair p-4 (rows issued 2 iterations ago)
            float va0 = __int_as_float(ea0.y), va1 = __int_as_float(ea1.y);
            acc8(acc, va0, xa0);
            acc8(acc, va1, xa1);
            if (SUMV) s += va0 + va1;
            // shift pipeline
            ea0 = eb0; ea1 = eb1; eb0 = ec0; eb1 = ec1;
            ec0 = ed0; ec1 = ed1; ed0 = ee0; ed1 = ee1;
            xa0 = xb0; xa1 = xb1; xb0 = xc0; xb1 = xc1;
        }
        // drain: pipe holds pairs A(rows xa), B(rows xb), C(cols ec), D(cols ed)
        uint4 xc0 = ldrow(x, ec0.x, li), xc1 = ldrow(x, ec1.x, li);
        uint4 xd0 = ldrow(x, ed0.x, li), xd1 = ldrow(x, ed1.x, li);
        {
            float va0 = __int_as_float(ea0.y), va1 = __int_as_float(ea1.y);
            acc8(acc, va0, xa0); acc8(acc, va1, xa1);
            if (SUMV) s += va0 + va1;
        }
        {
            float vb0 = __int_as_float(eb0.y), vb1 = __int_as_float(eb1.y);
            acc8(acc, vb0, xb0); acc8(acc, vb1, xb1);
            if (SUMV) s += vb0 + vb1;
        }
        {
            float vc0 = __int_as_float(ec0.y), vc1 = __int_as_float(ec1.y);
            acc8(acc, vc0, xc0); acc8(acc, vc1, xc1);
            if (SUMV) s += vc0 + vc1;
        }
        {
            float vd0 = __int_as_float(ed0.y), vd1 = __int_as_float(ed1.y);
            acc8(acc, vd0, xd0); acc8(acc, vd1, xd1);
            if (SUMV) s += vd0 + vd1;
        }
        if (n & 1) {
            i2v eq = ep[n - 1];
            float v = __int_as_float(eq.y);
            uint4 xq = ldrow(x, eq.x, li);
            acc8(acc, v, xq);
            if (SUMV) s += v;
        }
    } else {
        for (int e = 0; e < n; ++e) {
            i2v eq = ep[e];
            float v = __int_as_float(eq.y);
            uint4 xq = ldrow(x, eq.x, li);
            acc8(acc, v, xq);
            if (SUMV) s += v;
        }
    }
    if (SUMV) *vsum = s;
}

// ---------------------------------------------------------------------------
// K1: fused theta-softmax + exp_v + path-stream pack.
// ---------------------------------------------------------------------------
__global__ void k_expv_pack(const float* __restrict__ p_counts,
                            const float* __restrict__ theta,
                            const int* __restrict__ p_col,
                            i2v* __restrict__ pev, int E) {
    int i = blockIdx.x * blockDim.x + threadIdx.x;
    if (i >= E) return;
    float m = -1e30f;
    for (int k = 0; k < 6; ++k) m = fmaxf(m, theta[k]);
    float e[6];
    float s = 0.f;
    for (int k = 0; k < 6; ++k) { e[k] = expf(theta[k] - m); s += e[k]; }
    float w0 = e[0] / s, w1 = e[1] / s, w2 = e[2] / s,
          w3 = e[3] / s, w4 = e[4] / s, w5 = e[5] / s;
    const float* c = p_counts + (size_t)i * 6;
    float v = c[0] * w0 + c[1] * w1 + c[2] * w2 +
              c[3] * w3 + c[4] * w4 + c[5] * w5;
    i2v o;
    o.x = __builtin_nontemporal_load(p_col + i);
    o.y = __float_as_int(expf(v));
    __builtin_nontemporal_store(o, pev + i);
}

// ---------------------------------------------------------------------------
// K2: all CSR row_ptr arrays in one launch (rows sorted: np.unique).
//     Segment 3 computes rp_m[r] = rp_pos[r] + rp_neg[r] (merged graph).
//     Threads t<512 also zero the degree-histogram bins (used later).
// ---------------------------------------------------------------------------
__device__ __forceinline__ int lower_bound_v(const int* __restrict__ rows,
                                             int nnz, int r) {
    int lo = 0, hi = nnz;
    while (lo < hi) {
        int mid = (lo + hi) >> 1;
        if (rows[mid] < r) lo = mid + 1; else hi = mid;
    }
    return lo;
}

__global__ void k_row_ptr4(const int* __restrict__ rows_a, int nnz_a, int* __restrict__ pa,
                           const int* __restrict__ rows_b, int nnz_b, int* __restrict__ pb,
                           const int* __restrict__ rows_c, int nnz_c, int* __restrict__ pc,
                           int* __restrict__ pm, int* __restrict__ bins) {
    int t = blockIdx.x * blockDim.x + threadIdx.x;
    if (t < 512) bins[t] = 0;
    int which = t / (NUM_NODES + 1);
    int r = t - which * (NUM_NODES + 1);
    if (which == 0) pa[r] = lower_bound_v(rows_a, nnz_a, r);
    else if (which == 1) pb[r] = lower_bound_v(rows_b, nnz_b, r);
    else if (which == 2) pc[r] = lower_bound_v(rows_c, nnz_c, r);
    else if (which == 3) pm[r] = lower_bound_v(rows_a, nnz_a, r) +
                                 lower_bound_v(rows_b, nnz_b, r);
}

// ---------------------------------------------------------------------------
// K2b/K2c/K2d: counting sort of rows by degree, for merged graph (which=0)
// and path graph (which=1). Produces meta[pos] = {start, end, orig_row, 0}
// with pos ascending in degree. Waves then get near-equal-degree rows.
// Permutation is atomic-ticket nondeterministic; output VALUES are not
// affected (each row's own arithmetic and output slot are unchanged).
// ---------------------------------------------------------------------------
__global__ void k_deg_hist(const int* __restrict__ rp_m,
                           const int* __restrict__ rp_p,
                           int* __restrict__ bins) {
    int t = blockIdx.x * blockDim.x + threadIdx.x;
    if (t >= 2 * NUM_NODES) return;
    int which = t >= NUM_NODES;
    int r = t - which * NUM_NODES;
    const int* rp = which ? rp_p : rp_m;
    int deg = rp[r + 1] - rp[r];
    int b = deg < 255 ? deg : 255;
    atomicAdd(bins + which * 256 + b, 1);
}

__global__ void k_deg_scan(const int* __restrict__ bins,
                           int* __restrict__ bases) {
    int w = threadIdx.x;   // 0,1
    if (w < 2) {
        int run = 0;
        for (int b = 0; b < 256; ++b) {
            bases[w * 256 + b] = run;
            run += bins[w * 256 + b];
        }
    }
}

__global__ void k_deg_scatter(const int* __restrict__ rp_m,
                              const int* __restrict__ rp_p,
                              int* __restrict__ bases,
                              int4* __restrict__ meta_m,
                              int4* __restrict__ meta_p) {
    int t = blockIdx.x * blockDim.x + threadIdx.x;
    if (t >= 2 * NUM_NODES) return;
    int which = t >= NUM_NODES;
    int r = t - which * NUM_NODES;
    const int* rp = which ? rp_p : rp_m;
    int s = rp[r], e = rp[r + 1];
    int deg = e - s;
    int b = deg < 255 ? deg : 255;
    int pos = atomicAdd(bases + which * 256 + b, 1);
    int4 md; md.x = s; md.y = e; md.z = r; md.w = 0;
    (which ? meta_p : meta_m)[pos] = md;
}

// ---------------------------------------------------------------------------
// K3: convert user_emb || item_emb (fp32) -> bf16 table
// ---------------------------------------------------------------------------
__global__ void k_cvt(const float* __restrict__ user_emb,
                      const float* __restrict__ item_emb,
                      u16* __restrict__ emb16) {
    int i = blockIdx.x * blockDim.x + threadIdx.x;   // handles 4 floats
    size_t f = (size_t)i * 4;
    const size_t UTOT = (size_t)NUM_USERS * DIM;
    const size_t TOT = (size_t)NUM_NODES * DIM;
    if (f >= TOT) return;
    f4v v = (f < UTOT) ? __builtin_nontemporal_load((const f4v*)(user_emb + f))
                       : __builtin_nontemporal_load((const f4v*)(item_emb + (f - UTOT)));
    ushort4 o;
    o.x = f2bf(v.x); o.y = f2bf(v.y); o.z = f2bf(v.z); o.w = f2bf(v.w);
    *(ushort4*)(emb16 + f) = o;   // normal store: k_path gathers from this next
}

// ---------------------------------------------------------------------------
// K4: EDGE-PARALLEL merge of pos+neg CSR into one packed pre-scaled stream.
// ---------------------------------------------------------------------------
__global__ void k_merge_e(const int* __restrict__ row_p, const int* __restrict__ col_p,
                          const float* __restrict__ val_p,
                          const int* __restrict__ row_n, const int* __restrict__ col_n,
                          const float* __restrict__ val_n,
                          const int* __restrict__ rp_p, const int* __restrict__ rp_n,
                          i2v* __restrict__ mev, int E_pos, int E_tot) {
    int g = blockIdx.x * blockDim.x + threadIdx.x;
    if (g >= E_tot) return;
    if (g < E_pos) {
        int r = __builtin_nontemporal_load(row_p + g);
        i2v e;
        e.x = __builtin_nontemporal_load(col_p + g);
        e.y = __float_as_int(__builtin_nontemporal_load(val_p + g));
        __builtin_nontemporal_store(e, mev + (size_t)g + rp_n[r]);
    } else {
        int i = g - E_pos;
        int r = __builtin_nontemporal_load(row_n + i);
        i2v e;
        e.x = __builtin_nontemporal_load(col_n + i);
        e.y = __float_as_int(-ALPHA_C * __builtin_nontemporal_load(val_n + i));
        __builtin_nontemporal_store(e, mev + (size_t)i + rp_p[r + 1]);
    }
}

// ---------------------------------------------------------------------------
// K5: path SpMM with fused row-softmax over packed {col,exp_v} stream.
//     Degree-sorted via meta_p; output scattered to original row.
// ---------------------------------------------------------------------------
__global__ void k_path(const u16* __restrict__ emb16,
                       const i2v* __restrict__ pev,
                       const int4* __restrict__ meta_p,
                       u16* __restrict__ e0) {
    int t = blockIdx.x * blockDim.x + threadIdx.x;
    int g = t >> 3;
    if (g >= NUM_NODES) return;
    int li = threadIdx.x & 7;
    int4 md = meta_p[g];          // same addr across the 8 lanes -> broadcast

    float acc[8];
#pragma unroll
    for (int k = 0; k < 8; ++k) acc[k] = 0.f;
    float s = 0.f;

    seg_pipe<true>(pev, md.x, md.y, emb16, li, acc, &s);

    float inv = 1.0f / (s + 1e-12f);
    u32 o[4];
#pragma unroll
    for (int k = 0; k < 4; ++k)
        o[k] = (u32)f2bf(acc[2 * k] * inv) | ((u32)f2bf(acc[2 * k + 1] * inv) << 16);
    *((uint4*)(e0 + (size_t)md.z * DIM) + li) = *(uint4*)o;
}

// ---------------------------------------------------------------------------
// K6: one propagation layer over the merged pre-scaled stream.
//     Degree-sorted via meta_m; all reads/writes use the original row id.
// ---------------------------------------------------------------------------
template <int FINAL>
__global__ void k_layer_t(const u16* __restrict__ e_in,
                          u16* __restrict__ e_out,
                          const u16* __restrict__ e0,
                          const u16* __restrict__ e1,
                          float* __restrict__ out,
                          const int4* __restrict__ meta_m,
                          const i2v* __restrict__ mev) {
    int t = blockIdx.x * blockDim.x + threadIdx.x;
    int g = t >> 3;
    if (g >= NUM_NODES) return;
    int li = threadIdx.x & 7;
    int4 md = meta_m[g];          // {start, end, orig_row}

    // own-row read issued BEFORE the walk (oldest in VMEM queue -> free wait)
    uint4 eq = *((const uint4*)(e_in + (size_t)md.z * DIM) + li);

    float acc[8];
#pragma unroll
    for (int k = 0; k < 8; ++k) acc[k] = 0.f;

    seg_pipe<false>(mev, md.x, md.y, e_in, li, acc, nullptr);

    const u32* ep_ = (const u32*)&eq;
    float res[8];
#pragma unroll
    for (int k = 0; k < 4; ++k) {
        res[2 * k]     = acc[2 * k]     + ALPHA_C * lo_bf(ep_[k]);
        res[2 * k + 1] = acc[2 * k + 1] + ALPHA_C * hi_bf(ep_[k]);
    }

    if (FINAL) {
        u4v q0 = __builtin_nontemporal_load((const u4v*)(e0 + (size_t)md.z * DIM) + li);
        u4v q1 = __builtin_nontemporal_load((const u4v*)(e1 + (size_t)md.z * DIM) + li);
        float of[8];
#pragma unroll
        for (int k = 0; k < 4; ++k) {
            float lo = res[2 * k]     + lo_bf(ep_[k]) + lo_bf(q0[k]) + lo_bf(q1[k]);
            float hi = res[2 * k + 1] + hi_bf(ep_[k]) + hi_bf(q0[k]) + hi_bf(q1[k]);
            of[2 * k]     = 0.25f * lo;
            of[2 * k + 1] = 0.25f * hi;
        }
        f4v o0, o1;
        o0.x = of[0]; o0.y = of[1]; o0.z = of[2]; o0.w = of[3];
        o1.x = of[4]; o1.y = of[5]; o1.z = of[6]; o1.w = of[7];
        f4v* sp = (f4v*)(out + (size_t)md.z * DIM) + li * 2;
        __builtin_nontemporal_store(o0, sp);
        __builtin_nontemporal_store(o1, sp + 1);
    } else {
        u32 o[4];
#pragma unroll
        for (int k = 0; k < 4; ++k)
            o[k] = (u32)f2bf(res[2 * k]) | ((u32)f2bf(res[2 * k + 1]) << 16);
        *((uint4*)(e_out + (size_t)md.z * DIM) + li) = *(uint4*)o;
    }
}

// ---------------------------------------------------------------------------
extern "C" void kernel_launch(void* const* d_in, const int* in_sizes, int n_in,
                              void* d_out, int out_size, void* d_ws, size_t ws_size,
                              hipStream_t stream) {
    const float* user_emb = (const float*)d_in[0];
    const float* item_emb = (const float*)d_in[1];
    const float* theta    = (const float*)d_in[2];
    const int*   pos_row  = (const int*)d_in[3];
    const int*   pos_col  = (const int*)d_in[4];
    const float* pos_val  = (const float*)d_in[5];
    const int*   neg_row  = (const int*)d_in[6];
    const int*   neg_col  = (const int*)d_in[7];
    const float* neg_val  = (const float*)d_in[8];
    const int*   p_row    = (const int*)d_in[9];
    const int*   p_col    = (const int*)d_in[10];
    const float* p_counts = (const float*)d_in[11];
    const int E_pos  = in_sizes[3];
    const int E_neg  = in_sizes[6];
    const int E_path = in_sizes[9];

    // bump allocator over d_ws (256B aligned chunks)
    char* wsb = (char*)d_ws;
    size_t off = 0;
    auto alloc = [&](size_t bytes) -> void* {
        void* p = wsb + off;
        off = (off + bytes + 255) & ~(size_t)255;
        return p;
    };
    i2v*   pev     = (i2v*)alloc((size_t)E_path * sizeof(i2v));
    int*   rp_pos  = (int*)alloc((size_t)(NUM_NODES + 1) * sizeof(int));
    int*   rp_neg  = (int*)alloc((size_t)(NUM_NODES + 1) * sizeof(int));
    int*   rp_path = (int*)alloc((size_t)(NUM_NODES + 1) * sizeof(int));
    int*   rp_m    = (int*)alloc((size_t)(NUM_NODES + 1) * sizeof(int));
    int*   bins    = (int*)alloc(512 * sizeof(int));
    int*   bases   = (int*)alloc(512 * sizeof(int));
    int4*  meta_m  = (int4*)alloc((size_t)NUM_NODES * sizeof(int4));
    int4*  meta_p  = (int4*)alloc((size_t)NUM_NODES * sizeof(int4));
    i2v*   mev     = (i2v*)alloc((size_t)(E_pos + E_neg) * sizeof(i2v));
    u16*   emb16   = (u16*)alloc((size_t)NUM_NODES * DIM * sizeof(u16));
    u16*   e0      = (u16*)alloc((size_t)NUM_NODES * DIM * sizeof(u16));
    u16*   e1      = (u16*)alloc((size_t)NUM_NODES * DIM * sizeof(u16));
    u16*   e2      = emb16;   // emb16 is dead after k_path; reuse for e2
    float* outp    = (float*)d_out;

    k_expv_pack<<<(E_path + 255) / 256, 256, 0, stream>>>(p_counts, theta, p_col,
                                                          pev, E_path);

    int total_rp = 4 * (NUM_NODES + 1);
    k_row_ptr4<<<(total_rp + 255) / 256, 256, 0, stream>>>(
        pos_row, E_pos, rp_pos, neg_row, E_neg, rp_neg, p_row, E_path, rp_path,
        rp_m, bins);

    int cvt_threads = (NUM_NODES * DIM) / 4;
    k_cvt<<<(cvt_threads + 255) / 256, 256, 0, stream>>>(user_emb, item_emb, emb16);

    int E_tot = E_pos + E_neg;
    k_merge_e<<<(E_tot + 255) / 256, 256, 0, stream>>>(
        pos_row, pos_col, pos_val, neg_row, neg_col, neg_val,
        rp_pos, rp_neg, mev, E_pos, E_tot);

    // degree sort (both graphs): hist -> scan -> scatter into meta tables
    int nh = 2 * NUM_NODES;
    k_deg_hist<<<(nh + 255) / 256, 256, 0, stream>>>(rp_m, rp_path, bins);
    k_deg_scan<<<1, 64, 0, stream>>>(bins, bases);
    k_deg_scatter<<<(nh + 255) / 256, 256, 0, stream>>>(rp_m, rp_path, bases,
                                                        meta_m, meta_p);

    // one 8-lane group per sorted row slot: 32 rows per 256-thread block
    int row_blocks = (NUM_NODES + 31) / 32;  // 3750

    k_path<<<row_blocks, 256, 0, stream>>>(emb16, pev, meta_p, e0);
    k_layer_t<0><<<row_blocks, 256, 0, stream>>>(e0, e1, nullptr, nullptr, nullptr,
                                                 meta_m, mev);
    k_layer_t<0><<<row_blocks, 256, 0, stream>>>(e1, e2, nullptr, nullptr, nullptr,
                                                 meta_m, mev);
    k_layer_t<1><<<row_blocks, 256, 0, stream>>>(e2, nullptr, e0, e1, outp,
                                                 meta_m, mev);
}

// Round 5
// 509.221 us; speedup vs baseline: 2.8145x; 2.8145x over previous
//
#include <hip/hip_runtime.h>

#define NUM_USERS 80000
#define NUM_ITEMS 40000
#define NUM_NODES 120000
#define DIM 64
#define ALPHA_C 0.8f

typedef unsigned short u16;
typedef unsigned int u32;
typedef int   i2v __attribute__((ext_vector_type(2)));
typedef u32   u4v __attribute__((ext_vector_type(4)));
typedef float f4v __attribute__((ext_vector_type(4)));

// fp32 -> bf16 round-nearest-even
__device__ __forceinline__ u16 f2bf(float f) {
    union { float f; u32 i; } v;
    v.f = f;
    u32 i = v.i;
    u32 r = (i + 0x7FFFu + ((i >> 16) & 1u)) >> 16;
    return (u16)r;
}
__device__ __forceinline__ float lo_bf(u32 u) { return __uint_as_float(u << 16); }
__device__ __forceinline__ float hi_bf(u32 u) { return __uint_as_float(u & 0xffff0000u); }

// accumulate 8 bf16 (packed in uint4) * v into acc[8]
__device__ __forceinline__ void acc8(float* __restrict__ acc, float v, uint4 q) {
    const u32* p = (const u32*)&q;
#pragma unroll
    for (int k = 0; k < 4; ++k) {
        u32 u = p[k];
        acc[2 * k]     = fmaf(v, lo_bf(u), acc[2 * k]);
        acc[2 * k + 1] = fmaf(v, hi_bf(u), acc[2 * k + 1]);
    }
}

__device__ __forceinline__ uint4 ldrow(const u16* __restrict__ x, int c, int li) {
    return *((const uint4*)(x + (size_t)c * DIM) + li);
}

// ---------------------------------------------------------------------------
// Depth-4 software-pipelined segment gather over a PACKED {col,val} stream.
// 8-lane group walks its segment. Per iteration: load edge-pair p, issue
// row gathers for pair p-2, consume pair p-4.
// NOTE (R2 lesson): edge loads MUST be normal cached loads, not nontemporal.
// R4/R5: rows are degree-sorted by the caller so the 8 groups of a wave have
// near-equal n -> the EXEC-masked max(n)-makespan waste collapses.
// Per-row arithmetic and order unchanged -> outputs bitwise identical.
// ---------------------------------------------------------------------------
template <bool SUMV>
__device__ __forceinline__ void seg_pipe(const i2v* __restrict__ ep0,
                                         int start, int end,
                                         const u16* __restrict__ x,
                                         int li,
                                         float* __restrict__ acc,
                                         float* __restrict__ vsum) {
    const int n = end - start;
    const i2v* ep = ep0 + start;
    float s = 0.f;
    const int np = n >> 1;
    if (np >= 4) {
        i2v ea0 = ep[0], ea1 = ep[1];
        i2v eb0 = ep[2], eb1 = ep[3];
        i2v ec0 = ep[4], ec1 = ep[5];
        i2v ed0 = ep[6], ed1 = ep[7];
        uint4 xa0 = ldrow(x, ea0.x, li), xa1 = ldrow(x, ea1.x, li);
        uint4 xb0 = ldrow(x, eb0.x, li), xb1 = ldrow(x, eb1.x, li);
        for (int p = 4; p < np; ++p) {
            // E: prefetch edge pair p (2 iterations ahead of its gather)
            i2v ee0 = ep[2 * p];
            i2v ee1 = ep[2 * p + 1];
            // G: issue row gathers for pair p-2 (edges arrived long ago)
            uint4 xc0 = ldrow(x, ec0.x, li);
            uint4 xc1 = ldrow(x, ec1.x, li);
            // C: consume pair p-4 (rows issued 2 iterations ago)
            float va0 = __int_as_float(ea0.y), va1 = __int_as_float(ea1.y);
            acc8(acc, va0, xa0);
            acc8(acc, va1, xa1);
            if (SUMV) s += va0 + va1;
            // shift pipeline
            ea0 = eb0; ea1 = eb1; eb0 = ec0; eb1 = ec1;
            ec0 = ed0; ec1 = ed1; ed0 = ee0; ed1 = ee1;
            xa0 = xb0; xa1 = xb1; xb0 = xc0; xb1 = xc1;
        }
        // drain: pipe holds pairs A(rows xa), B(rows xb), C(cols ec), D(cols ed)
        uint4 xc0 = ldrow(x, ec0.x, li), xc1 = ldrow(x, ec1.x, li);
        uint4 xd0 = ldrow(x, ed0.x, li), xd1 = ldrow(x, ed1.x, li);
        {
            float va0 = __int_as_float(ea0.y), va1 = __int_as_float(ea1.y);
            acc8(acc, va0, xa0); acc8(acc, va1, xa1);
            if (SUMV) s += va0 + va1;
        }
        {
            float vb0 = __int_as_float(eb0.y), vb1 = __int_as_float(eb1.y);
            acc8(acc, vb0, xb0); acc8(acc, vb1, xb1);
            if (SUMV) s += vb0 + vb1;
        }
        {
            float vc0 = __int_as_float(ec0.y), vc1 = __int_as_float(ec1.y);
            acc8(acc, vc0, xc0); acc8(acc, vc1, xc1);
            if (SUMV) s += vc0 + vc1;
        }
        {
            float vd0 = __int_as_float(ed0.y), vd1 = __int_as_float(ed1.y);
            acc8(acc, vd0, xd0); acc8(acc, vd1, xd1);
            if (SUMV) s += vd0 + vd1;
        }
        if (n & 1) {
            i2v eq = ep[n - 1];
            float v = __int_as_float(eq.y);
            uint4 xq = ldrow(x, eq.x, li);
            acc8(acc, v, xq);
            if (SUMV) s += v;
        }
    } else {
        for (int e = 0; e < n; ++e) {
            i2v eq = ep[e];
            float v = __int_as_float(eq.y);
            uint4 xq = ldrow(x, eq.x, li);
            acc8(acc, v, xq);
            if (SUMV) s += v;
        }
    }
    if (SUMV) *vsum = s;
}

// ---------------------------------------------------------------------------
// K1: fused theta-softmax + exp_v + path-stream pack.
// ---------------------------------------------------------------------------
__global__ void k_expv_pack(const float* __restrict__ p_counts,
                            const float* __restrict__ theta,
                            const int* __restrict__ p_col,
                            i2v* __restrict__ pev, int E) {
    int i = blockIdx.x * blockDim.x + threadIdx.x;
    if (i >= E) return;
    float m = -1e30f;
    for (int k = 0; k < 6; ++k) m = fmaxf(m, theta[k]);
    float e[6];
    float s = 0.f;
    for (int k = 0; k < 6; ++k) { e[k] = expf(theta[k] - m); s += e[k]; }
    float w0 = e[0] / s, w1 = e[1] / s, w2 = e[2] / s,
          w3 = e[3] / s, w4 = e[4] / s, w5 = e[5] / s;
    const float* c = p_counts + (size_t)i * 6;
    float v = c[0] * w0 + c[1] * w1 + c[2] * w2 +
              c[3] * w3 + c[4] * w4 + c[5] * w5;
    i2v o;
    o.x = __builtin_nontemporal_load(p_col + i);
    o.y = __float_as_int(expf(v));
    __builtin_nontemporal_store(o, pev + i);
}

// ---------------------------------------------------------------------------
// K2: all CSR row_ptr arrays in one launch (rows sorted: np.unique).
//     Segment 3 computes rp_m[r] = rp_pos[r] + rp_neg[r] (merged graph).
//     Threads t<512 also zero the degree-histogram bins (used later).
// ---------------------------------------------------------------------------
__device__ __forceinline__ int lower_bound_v(const int* __restrict__ rows,
                                             int nnz, int r) {
    int lo = 0, hi = nnz;
    while (lo < hi) {
        int mid = (lo + hi) >> 1;
        if (rows[mid] < r) lo = mid + 1; else hi = mid;
    }
    return lo;
}

__global__ void k_row_ptr4(const int* __restrict__ rows_a, int nnz_a, int* __restrict__ pa,
                           const int* __restrict__ rows_b, int nnz_b, int* __restrict__ pb,
                           const int* __restrict__ rows_c, int nnz_c, int* __restrict__ pc,
                           int* __restrict__ pm, int* __restrict__ bins) {
    int t = blockIdx.x * blockDim.x + threadIdx.x;
    if (t < 512) bins[t] = 0;
    int which = t / (NUM_NODES + 1);
    int r = t - which * (NUM_NODES + 1);
    if (which == 0) pa[r] = lower_bound_v(rows_a, nnz_a, r);
    else if (which == 1) pb[r] = lower_bound_v(rows_b, nnz_b, r);
    else if (which == 2) pc[r] = lower_bound_v(rows_c, nnz_c, r);
    else if (which == 3) pm[r] = lower_bound_v(rows_a, nnz_a, r) +
                                 lower_bound_v(rows_b, nnz_b, r);
}

// ---------------------------------------------------------------------------
// Counting sort of rows by degree (merged graph: which=0, path: which=1).
// R5 lesson (R4 post-mortem): 240k naive global atomics onto ~60 hot bins
// serialize on the modal bin (~12k x ~40ns = ~500us PER KERNEL). Fix per
// Guideline 12: LDS-aggregate per block, then ONE global atomic per
// (block, present-bin) -> max per-address chain = #blocks (938), concurrent
// across bins. Permutation differs from R4's but any permutation is valid:
// each row's own arithmetic and output slot are unchanged.
// ---------------------------------------------------------------------------
__global__ void k_deg_hist(const int* __restrict__ rp_m,
                           const int* __restrict__ rp_p,
                           int* __restrict__ bins) {
    __shared__ int lh[512];
    int tid = threadIdx.x;
    lh[tid] = 0; lh[tid + 256] = 0;
    __syncthreads();
    int t = blockIdx.x * 256 + tid;
    if (t < 2 * NUM_NODES) {
        int which = t >= NUM_NODES;
        int r = t - which * NUM_NODES;
        const int* rp = which ? rp_p : rp_m;
        int deg = rp[r + 1] - rp[r];
        int b = deg < 255 ? deg : 255;
        atomicAdd(&lh[which * 256 + b], 1);
    }
    __syncthreads();
    int c0 = lh[tid];       if (c0) atomicAdd(bins + tid, c0);
    int c1 = lh[tid + 256]; if (c1) atomicAdd(bins + 256 + tid, c1);
}

__global__ void k_deg_scan(const int* __restrict__ bins,
                           int* __restrict__ bases) {
    int w = threadIdx.x;   // 0,1
    if (w < 2) {
        int run = 0;
        for (int b = 0; b < 256; ++b) {
            bases[w * 256 + b] = run;
            run += bins[w * 256 + b];
        }
    }
}

__global__ void k_deg_scatter(const int* __restrict__ rp_m,
                              const int* __restrict__ rp_p,
                              int* __restrict__ bases,
                              int4* __restrict__ meta_m,
                              int4* __restrict__ meta_p) {
    __shared__ int lh[512];   // local per-bin counts
    __shared__ int lb[512];   // this block's global base per bin
    int tid = threadIdx.x;
    lh[tid] = 0; lh[tid + 256] = 0;
    __syncthreads();
    int t = blockIdx.x * 256 + tid;
    int which = 0, bin = 0, lrank = 0, s = 0, e = 0, r = 0;
    bool valid = t < 2 * NUM_NODES;
    if (valid) {
        which = t >= NUM_NODES;
        r = t - which * NUM_NODES;
        const int* rp = which ? rp_p : rp_m;
        s = rp[r]; e = rp[r + 1];
        int deg = e - s;
        bin = which * 256 + (deg < 255 ? deg : 255);
        lrank = atomicAdd(&lh[bin], 1);          // LDS atomic: intra-block rank
    }
    __syncthreads();
    int c0 = lh[tid];       if (c0) lb[tid]       = atomicAdd(bases + tid, c0);
    int c1 = lh[tid + 256]; if (c1) lb[tid + 256] = atomicAdd(bases + 256 + tid, c1);
    __syncthreads();
    if (valid) {
        int pos = lb[bin] + lrank;
        int4 md; md.x = s; md.y = e; md.z = r; md.w = 0;
        (which ? meta_p : meta_m)[pos] = md;
    }
}

// ---------------------------------------------------------------------------
// K3: convert user_emb || item_emb (fp32) -> bf16 table
// ---------------------------------------------------------------------------
__global__ void k_cvt(const float* __restrict__ user_emb,
                      const float* __restrict__ item_emb,
                      u16* __restrict__ emb16) {
    int i = blockIdx.x * blockDim.x + threadIdx.x;   // handles 4 floats
    size_t f = (size_t)i * 4;
    const size_t UTOT = (size_t)NUM_USERS * DIM;
    const size_t TOT = (size_t)NUM_NODES * DIM;
    if (f >= TOT) return;
    f4v v = (f < UTOT) ? __builtin_nontemporal_load((const f4v*)(user_emb + f))
                       : __builtin_nontemporal_load((const f4v*)(item_emb + (f - UTOT)));
    ushort4 o;
    o.x = f2bf(v.x); o.y = f2bf(v.y); o.z = f2bf(v.z); o.w = f2bf(v.w);
    *(ushort4*)(emb16 + f) = o;   // normal store: k_path gathers from this next
}

// ---------------------------------------------------------------------------
// K4: EDGE-PARALLEL merge of pos+neg CSR into one packed pre-scaled stream.
// ---------------------------------------------------------------------------
__global__ void k_merge_e(const int* __restrict__ row_p, const int* __restrict__ col_p,
                          const float* __restrict__ val_p,
                          const int* __restrict__ row_n, const int* __restrict__ col_n,
                          const float* __restrict__ val_n,
                          const int* __restrict__ rp_p, const int* __restrict__ rp_n,
                          i2v* __restrict__ mev, int E_pos, int E_tot) {
    int g = blockIdx.x * blockDim.x + threadIdx.x;
    if (g >= E_tot) return;
    if (g < E_pos) {
        int r = __builtin_nontemporal_load(row_p + g);
        i2v e;
        e.x = __builtin_nontemporal_load(col_p + g);
        e.y = __float_as_int(__builtin_nontemporal_load(val_p + g));
        __builtin_nontemporal_store(e, mev + (size_t)g + rp_n[r]);
    } else {
        int i = g - E_pos;
        int r = __builtin_nontemporal_load(row_n + i);
        i2v e;
        e.x = __builtin_nontemporal_load(col_n + i);
        e.y = __float_as_int(-ALPHA_C * __builtin_nontemporal_load(val_n + i));
        __builtin_nontemporal_store(e, mev + (size_t)i + rp_p[r + 1]);
    }
}

// ---------------------------------------------------------------------------
// K5: path SpMM with fused row-softmax over packed {col,exp_v} stream.
//     Degree-sorted via meta_p; output scattered to original row.
// ---------------------------------------------------------------------------
__global__ void k_path(const u16* __restrict__ emb16,
                       const i2v* __restrict__ pev,
                       const int4* __restrict__ meta_p,
                       u16* __restrict__ e0) {
    int t = blockIdx.x * blockDim.x + threadIdx.x;
    int g = t >> 3;
    if (g >= NUM_NODES) return;
    int li = threadIdx.x & 7;
    int4 md = meta_p[g];          // same addr across the 8 lanes -> broadcast

    float acc[8];
#pragma unroll
    for (int k = 0; k < 8; ++k) acc[k] = 0.f;
    float s = 0.f;

    seg_pipe<true>(pev, md.x, md.y, emb16, li, acc, &s);

    float inv = 1.0f / (s + 1e-12f);
    u32 o[4];
#pragma unroll
    for (int k = 0; k < 4; ++k)
        o[k] = (u32)f2bf(acc[2 * k] * inv) | ((u32)f2bf(acc[2 * k + 1] * inv) << 16);
    *((uint4*)(e0 + (size_t)md.z * DIM) + li) = *(uint4*)o;
}

// ---------------------------------------------------------------------------
// K6: one propagation layer over the merged pre-scaled stream.
//     Degree-sorted via meta_m; all reads/writes use the original row id.
// ---------------------------------------------------------------------------
template <int FINAL>
__global__ void k_layer_t(const u16* __restrict__ e_in,
                          u16* __restrict__ e_out,
                          const u16* __restrict__ e0,
                          const u16* __restrict__ e1,
                          float* __restrict__ out,
                          const int4* __restrict__ meta_m,
                          const i2v* __restrict__ mev) {
    int t = blockIdx.x * blockDim.x + threadIdx.x;
    int g = t >> 3;
    if (g >= NUM_NODES) return;
    int li = threadIdx.x & 7;
    int4 md = meta_m[g];          // {start, end, orig_row}

    // own-row read issued BEFORE the walk (oldest in VMEM queue -> free wait)
    uint4 eq = *((const uint4*)(e_in + (size_t)md.z * DIM) + li);

    float acc[8];
#pragma unroll
    for (int k = 0; k < 8; ++k) acc[k] = 0.f;

    seg_pipe<false>(mev, md.x, md.y, e_in, li, acc, nullptr);

    const u32* ep_ = (const u32*)&eq;
    float res[8];
#pragma unroll
    for (int k = 0; k < 4; ++k) {
        res[2 * k]     = acc[2 * k]     + ALPHA_C * lo_bf(ep_[k]);
        res[2 * k + 1] = acc[2 * k + 1] + ALPHA_C * hi_bf(ep_[k]);
    }

    if (FINAL) {
        u4v q0 = __builtin_nontemporal_load((const u4v*)(e0 + (size_t)md.z * DIM) + li);
        u4v q1 = __builtin_nontemporal_load((const u4v*)(e1 + (size_t)md.z * DIM) + li);
        float of[8];
#pragma unroll
        for (int k = 0; k < 4; ++k) {
            float lo = res[2 * k]     + lo_bf(ep_[k]) + lo_bf(q0[k]) + lo_bf(q1[k]);
            float hi = res[2 * k + 1] + hi_bf(ep_[k]) + hi_bf(q0[k]) + hi_bf(q1[k]);
            of[2 * k]     = 0.25f * lo;
            of[2 * k + 1] = 0.25f * hi;
        }
        f4v o0, o1;
        o0.x = of[0]; o0.y = of[1]; o0.z = of[2]; o0.w = of[3];
        o1.x = of[4]; o1.y = of[5]; o1.z = of[6]; o1.w = of[7];
        f4v* sp = (f4v*)(out + (size_t)md.z * DIM) + li * 2;
        __builtin_nontemporal_store(o0, sp);
        __builtin_nontemporal_store(o1, sp + 1);
    } else {
        u32 o[4];
#pragma unroll
        for (int k = 0; k < 4; ++k)
            o[k] = (u32)f2bf(res[2 * k]) | ((u32)f2bf(res[2 * k + 1]) << 16);
        *((uint4*)(e_out + (size_t)md.z * DIM) + li) = *(uint4*)o;
    }
}

// ---------------------------------------------------------------------------
extern "C" void kernel_launch(void* const* d_in, const int* in_sizes, int n_in,
                              void* d_out, int out_size, void* d_ws, size_t ws_size,
                              hipStream_t stream) {
    const float* user_emb = (const float*)d_in[0];
    const float* item_emb = (const float*)d_in[1];
    const float* theta    = (const float*)d_in[2];
    const int*   pos_row  = (const int*)d_in[3];
    const int*   pos_col  = (const int*)d_in[4];
    const float* pos_val  = (const float*)d_in[5];
    const int*   neg_row  = (const int*)d_in[6];
    const int*   neg_col  = (const int*)d_in[7];
    const float* neg_val  = (const float*)d_in[8];
    const int*   p_row    = (const int*)d_in[9];
    const int*   p_col    = (const int*)d_in[10];
    const float* p_counts = (const float*)d_in[11];
    const int E_pos  = in_sizes[3];
    const int E_neg  = in_sizes[6];
    const int E_path = in_sizes[9];

    // bump allocator over d_ws (256B aligned chunks)
    char* wsb = (char*)d_ws;
    size_t off = 0;
    auto alloc = [&](size_t bytes) -> void* {
        void* p = wsb + off;
        off = (off + bytes + 255) & ~(size_t)255;
        return p;
    };
    i2v*   pev     = (i2v*)alloc((size_t)E_path * sizeof(i2v));
    int*   rp_pos  = (int*)alloc((size_t)(NUM_NODES + 1) * sizeof(int));
    int*   rp_neg  = (int*)alloc((size_t)(NUM_NODES + 1) * sizeof(int));
    int*   rp_path = (int*)alloc((size_t)(NUM_NODES + 1) * sizeof(int));
    int*   rp_m    = (int*)alloc((size_t)(NUM_NODES + 1) * sizeof(int));
    int*   bins    = (int*)alloc(512 * sizeof(int));
    int*   bases   = (int*)alloc(512 * sizeof(int));
    int4*  meta_m  = (int4*)alloc((size_t)NUM_NODES * sizeof(int4));
    int4*  meta_p  = (int4*)alloc((size_t)NUM_NODES * sizeof(int4));
    i2v*   mev     = (i2v*)alloc((size_t)(E_pos + E_neg) * sizeof(i2v));
    u16*   emb16   = (u16*)alloc((size_t)NUM_NODES * DIM * sizeof(u16));
    u16*   e0      = (u16*)alloc((size_t)NUM_NODES * DIM * sizeof(u16));
    u16*   e1      = (u16*)alloc((size_t)NUM_NODES * DIM * sizeof(u16));
    u16*   e2      = emb16;   // emb16 is dead after k_path; reuse for e2
    float* outp    = (float*)d_out;

    k_expv_pack<<<(E_path + 255) / 256, 256, 0, stream>>>(p_counts, theta, p_col,
                                                          pev, E_path);

    int total_rp = 4 * (NUM_NODES + 1);
    k_row_ptr4<<<(total_rp + 255) / 256, 256, 0, stream>>>(
        pos_row, E_pos, rp_pos, neg_row, E_neg, rp_neg, p_row, E_path, rp_path,
        rp_m, bins);

    int cvt_threads = (NUM_NODES * DIM) / 4;
    k_cvt<<<(cvt_threads + 255) / 256, 256, 0, stream>>>(user_emb, item_emb, emb16);

    int E_tot = E_pos + E_neg;
    k_merge_e<<<(E_tot + 255) / 256, 256, 0, stream>>>(
        pos_row, pos_col, pos_val, neg_row, neg_col, neg_val,
        rp_pos, rp_neg, mev, E_pos, E_tot);

    // degree sort (both graphs): hist -> scan -> scatter into meta tables
    int nh = 2 * NUM_NODES;
    k_deg_hist<<<(nh + 255) / 256, 256, 0, stream>>>(rp_m, rp_path, bins);
    k_deg_scan<<<1, 64, 0, stream>>>(bins, bases);
    k_deg_scatter<<<(nh + 255) / 256, 256, 0, stream>>>(rp_m, rp_path, bases,
                                                        meta_m, meta_p);

    // one 8-lane group per sorted row slot: 32 rows per 256-thread block
    int row_blocks = (NUM_NODES + 31) / 32;  // 3750

    k_path<<<row_blocks, 256, 0, stream>>>(emb16, pev, meta_p, e0);
    k_layer_t<0><<<row_blocks, 256, 0, stream>>>(e0, e1, nullptr, nullptr, nullptr,
                                                 meta_m, mev);
    k_layer_t<0><<<row_blocks, 256, 0, stream>>>(e1, e2, nullptr, nullptr, nullptr,
                                                 meta_m, mev);
    k_layer_t<1><<<row_blocks, 256, 0, stream>>>(e2, nullptr, e0, e1, outp,
                                                 meta_m, mev);
}

// Round 6
// 480.214 us; speedup vs baseline: 2.9845x; 1.0604x over previous
//
#include <hip/hip_runtime.h>

#define NUM_USERS 80000
#define NUM_ITEMS 40000
#define NUM_NODES 120000
#define DIM 64
#define ALPHA_C 0.8f

typedef unsigned short u16;
typedef unsigned int u32;
typedef int   i2v __attribute__((ext_vector_type(2)));
typedef u32   u4v __attribute__((ext_vector_type(4)));
typedef float f4v __attribute__((ext_vector_type(4)));

// fp32 -> bf16 round-nearest-even
__device__ __forceinline__ u16 f2bf(float f) {
    union { float f; u32 i; } v;
    v.f = f;
    u32 i = v.i;
    u32 r = (i + 0x7FFFu + ((i >> 16) & 1u)) >> 16;
    return (u16)r;
}
__device__ __forceinline__ float lo_bf(u32 u) { return __uint_as_float(u << 16); }
__device__ __forceinline__ float hi_bf(u32 u) { return __uint_as_float(u & 0xffff0000u); }

// accumulate 8 bf16 (packed in uint4) * v into acc[8]
__device__ __forceinline__ void acc8(float* __restrict__ acc, float v, uint4 q) {
    const u32* p = (const u32*)&q;
#pragma unroll
    for (int k = 0; k < 4; ++k) {
        u32 u = p[k];
        acc[2 * k]     = fmaf(v, lo_bf(u), acc[2 * k]);
        acc[2 * k + 1] = fmaf(v, hi_bf(u), acc[2 * k + 1]);
    }
}

__device__ __forceinline__ uint4 ldrow(const u16* __restrict__ x, int c, int li) {
    return *((const uint4*)(x + (size_t)c * DIM) + li);
}

// ---------------------------------------------------------------------------
// Software-pipelined segment gather over a PACKED {col,val} stream.
// 8-lane group walks its segment in edge order (accumulation order is
// exactly 0,1,2,... -> bitwise identical outputs across rounds).
// R6 schedule: 4 resident edge-pairs (A..D) + 3 resident gather-pairs
// (xA..xC). Per iteration: load pair E, issue gathers for pair D, consume
// pair A (whose gathers were issued 3 iterations ago). At the consume-wait
// ~8 VMEM ops remain outstanding (was ~6 with 2 resident gather-pairs) ->
// +33% memory-level parallelism per wave.
// NOTE (R2 lesson): edge loads are NORMAL cached loads, never nontemporal
// (group touches each 64B line 4x).
// NOTE (R5 lesson): rows processed in natural order; degree-sorting trades
// away inter-group locality for lane balance and loses.
// ---------------------------------------------------------------------------
template <bool SUMV>
__device__ __forceinline__ void seg_pipe(const i2v* __restrict__ ep0,
                                         int start, int end,
                                         const u16* __restrict__ x,
                                         int li,
                                         float* __restrict__ acc,
                                         float* __restrict__ vsum) {
    const int n = end - start;
    const i2v* ep = ep0 + start;
    float s = 0.f;
    const int np = n >> 1;
    if (np >= 4) {
        i2v ea0 = ep[0], ea1 = ep[1];
        i2v eb0 = ep[2], eb1 = ep[3];
        i2v ec0 = ep[4], ec1 = ep[5];
        i2v ed0 = ep[6], ed1 = ep[7];
        uint4 xa0 = ldrow(x, ea0.x, li), xa1 = ldrow(x, ea1.x, li);
        uint4 xb0 = ldrow(x, eb0.x, li), xb1 = ldrow(x, eb1.x, li);
        uint4 xc0 = ldrow(x, ec0.x, li), xc1 = ldrow(x, ec1.x, li);
        for (int p = 4; p < np; ++p) {
            // E: prefetch edge pair p (1 iteration ahead of its gather;
            // edge stream is sequential/L2-hot, short latency suffices)
            i2v ee0 = ep[2 * p];
            i2v ee1 = ep[2 * p + 1];
            // G: issue row gathers for pair D (edges arrived last iter)
            uint4 xd0 = ldrow(x, ed0.x, li);
            uint4 xd1 = ldrow(x, ed1.x, li);
            // C: consume pair A (rows issued 3 iterations ago)
            float va0 = __int_as_float(ea0.y), va1 = __int_as_float(ea1.y);
            acc8(acc, va0, xa0);
            acc8(acc, va1, xa1);
            if (SUMV) s += va0 + va1;
            // shift pipeline
            ea0 = eb0; ea1 = eb1; eb0 = ec0; eb1 = ec1;
            ec0 = ed0; ec1 = ed1; ed0 = ee0; ed1 = ee1;
            xa0 = xb0; xa1 = xb1; xb0 = xc0; xb1 = xc1; xc0 = xd0; xc1 = xd1;
        }
        // drain: A,B,C hold gathers; D still needs its gather
        uint4 xd0 = ldrow(x, ed0.x, li), xd1 = ldrow(x, ed1.x, li);
        {
            float va0 = __int_as_float(ea0.y), va1 = __int_as_float(ea1.y);
            acc8(acc, va0, xa0); acc8(acc, va1, xa1);
            if (SUMV) s += va0 + va1;
        }
        {
            float vb0 = __int_as_float(eb0.y), vb1 = __int_as_float(eb1.y);
            acc8(acc, vb0, xb0); acc8(acc, vb1, xb1);
            if (SUMV) s += vb0 + vb1;
        }
        {
            float vc0 = __int_as_float(ec0.y), vc1 = __int_as_float(ec1.y);
            acc8(acc, vc0, xc0); acc8(acc, vc1, xc1);
            if (SUMV) s += vc0 + vc1;
        }
        {
            float vd0 = __int_as_float(ed0.y), vd1 = __int_as_float(ed1.y);
            acc8(acc, vd0, xd0); acc8(acc, vd1, xd1);
            if (SUMV) s += vd0 + vd1;
        }
        if (n & 1) {
            i2v eq = ep[n - 1];
            float v = __int_as_float(eq.y);
            uint4 xq = ldrow(x, eq.x, li);
            acc8(acc, v, xq);
            if (SUMV) s += v;
        }
    } else {
        for (int e = 0; e < n; ++e) {
            i2v eq = ep[e];
            float v = __int_as_float(eq.y);
            uint4 xq = ldrow(x, eq.x, li);
            acc8(acc, v, xq);
            if (SUMV) s += v;
        }
    }
    if (SUMV) *vsum = s;
}

__device__ __forceinline__ int lower_bound_v(const int* __restrict__ rows,
                                             int nnz, int r) {
    int lo = 0, hi = nnz;
    while (lo < hi) {
        int mid = (lo + hi) >> 1;
        if (rows[mid] < r) lo = mid + 1; else hi = mid;
    }
    return lo;
}

// ---------------------------------------------------------------------------
// K1 (fused prep): three independent jobs partitioned by blockIdx range --
//   [0, nb_expv)            : pev[i] = {p_col[i], exp(p_counts[i,:]·softmax)}
//   [nb_expv, +nb_cvt)      : user||item fp32 -> bf16 table
//   [nb_expv+nb_cvt, end)   : 4 CSR row_ptr arrays (pos, neg, path, merged)
// All expression chains identical to the previous round -> bitwise-same.
// ---------------------------------------------------------------------------
__global__ void k_prep(const float* __restrict__ p_counts,
                       const float* __restrict__ theta,
                       const int* __restrict__ p_col,
                       i2v* __restrict__ pev, int E_path,
                       const float* __restrict__ user_emb,
                       const float* __restrict__ item_emb,
                       u16* __restrict__ emb16,
                       const int* __restrict__ rows_a, int nnz_a, int* __restrict__ pa,
                       const int* __restrict__ rows_b, int nnz_b, int* __restrict__ pb,
                       const int* __restrict__ rows_c, int nnz_c, int* __restrict__ pc,
                       int* __restrict__ pm,
                       int nb_expv, int nb_cvt) {
    int b = blockIdx.x;
    int tid = threadIdx.x;
    if (b < nb_expv) {
        int i = b * 256 + tid;
        if (i >= E_path) return;
        float m = -1e30f;
        for (int k = 0; k < 6; ++k) m = fmaxf(m, theta[k]);
        float e[6];
        float s = 0.f;
        for (int k = 0; k < 6; ++k) { e[k] = expf(theta[k] - m); s += e[k]; }
        float w0 = e[0] / s, w1 = e[1] / s, w2 = e[2] / s,
              w3 = e[3] / s, w4 = e[4] / s, w5 = e[5] / s;
        const float* c = p_counts + (size_t)i * 6;
        float v = c[0] * w0 + c[1] * w1 + c[2] * w2 +
                  c[3] * w3 + c[4] * w4 + c[5] * w5;
        i2v o;
        o.x = __builtin_nontemporal_load(p_col + i);
        o.y = __float_as_int(expf(v));
        __builtin_nontemporal_store(o, pev + i);
    } else if (b < nb_expv + nb_cvt) {
        int i = (b - nb_expv) * 256 + tid;
        size_t f = (size_t)i * 4;
        const size_t UTOT = (size_t)NUM_USERS * DIM;
        const size_t TOT = (size_t)NUM_NODES * DIM;
        if (f >= TOT) return;
        f4v v = (f < UTOT)
            ? __builtin_nontemporal_load((const f4v*)(user_emb + f))
            : __builtin_nontemporal_load((const f4v*)(item_emb + (f - UTOT)));
        ushort4 o;
        o.x = f2bf(v.x); o.y = f2bf(v.y); o.z = f2bf(v.z); o.w = f2bf(v.w);
        *(ushort4*)(emb16 + f) = o;   // normal store: k_path gathers this next
    } else {
        int t = (b - nb_expv - nb_cvt) * 256 + tid;
        int which = t / (NUM_NODES + 1);
        int r = t - which * (NUM_NODES + 1);
        if (which == 0) pa[r] = lower_bound_v(rows_a, nnz_a, r);
        else if (which == 1) pb[r] = lower_bound_v(rows_b, nnz_b, r);
        else if (which == 2) pc[r] = lower_bound_v(rows_c, nnz_c, r);
        else if (which == 3) pm[r] = lower_bound_v(rows_a, nnz_a, r) +
                                     lower_bound_v(rows_b, nnz_b, r);
    }
}

// ---------------------------------------------------------------------------
// K2: EDGE-PARALLEL merge of pos+neg CSR into one packed pre-scaled stream.
//     pos edge g -> mev[g + rp_neg[row]] = {col,  val}
//     neg edge g -> mev[g + rp_pos[row+1]] = {col, -ALPHA*val}
//     Same per-row order (pos block then neg block) -> bitwise identical.
// ---------------------------------------------------------------------------
__global__ void k_merge_e(const int* __restrict__ row_p, const int* __restrict__ col_p,
                          const float* __restrict__ val_p,
                          const int* __restrict__ row_n, const int* __restrict__ col_n,
                          const float* __restrict__ val_n,
                          const int* __restrict__ rp_p, const int* __restrict__ rp_n,
                          i2v* __restrict__ mev, int E_pos, int E_tot) {
    int g = blockIdx.x * blockDim.x + threadIdx.x;
    if (g >= E_tot) return;
    if (g < E_pos) {
        int r = __builtin_nontemporal_load(row_p + g);
        i2v e;
        e.x = __builtin_nontemporal_load(col_p + g);
        e.y = __float_as_int(__builtin_nontemporal_load(val_p + g));
        __builtin_nontemporal_store(e, mev + (size_t)g + rp_n[r]);
    } else {
        int i = g - E_pos;
        int r = __builtin_nontemporal_load(row_n + i);
        i2v e;
        e.x = __builtin_nontemporal_load(col_n + i);
        e.y = __float_as_int(-ALPHA_C * __builtin_nontemporal_load(val_n + i));
        __builtin_nontemporal_store(e, mev + (size_t)i + rp_p[r + 1]);
    }
}

// ---------------------------------------------------------------------------
// K3: path SpMM with fused row-softmax over packed {col,exp_v} stream.
// ---------------------------------------------------------------------------
__global__ void k_path(const u16* __restrict__ emb16,
                       const i2v* __restrict__ pev,
                       const int* __restrict__ rp,
                       u16* __restrict__ e0) {
    int t = blockIdx.x * blockDim.x + threadIdx.x;
    int row = t >> 3;
    if (row >= NUM_NODES) return;
    int li = threadIdx.x & 7;
    int start = rp[row], end = rp[row + 1];

    float acc[8];
#pragma unroll
    for (int k = 0; k < 8; ++k) acc[k] = 0.f;
    float s = 0.f;

    seg_pipe<true>(pev, start, end, emb16, li, acc, &s);

    float inv = 1.0f / (s + 1e-12f);
    u32 o[4];
#pragma unroll
    for (int k = 0; k < 4; ++k)
        o[k] = (u32)f2bf(acc[2 * k] * inv) | ((u32)f2bf(acc[2 * k + 1] * inv) << 16);
    *((uint4*)(e0 + (size_t)row * DIM) + li) = *(uint4*)o;   // normal: gathered next
}

// ---------------------------------------------------------------------------
// K4: one propagation layer over the merged pre-scaled stream.
//     acc = sum_merged val*x ; res = acc + ALPHA*e_in
//     FINAL=0: write res (bf16) to e_out (normal store: next layer gathers it)
//     FINAL=1: out = 0.25*(e0 + e1 + e_in + res)  (fp32, nt, straight to d_out)
// ---------------------------------------------------------------------------
template <int FINAL>
__global__ void k_layer_t(const u16* __restrict__ e_in,
                          u16* __restrict__ e_out,
                          const u16* __restrict__ e0,
                          const u16* __restrict__ e1,
                          float* __restrict__ out,
                          const int* __restrict__ rp_m,
                          const i2v* __restrict__ mev) {
    int t = blockIdx.x * blockDim.x + threadIdx.x;
    int row = t >> 3;
    if (row >= NUM_NODES) return;
    int li = threadIdx.x & 7;

    // own-row read issued BEFORE the walk (oldest in VMEM queue -> free wait)
    uint4 eq = *((const uint4*)(e_in + (size_t)row * DIM) + li);

    float acc[8];
#pragma unroll
    for (int k = 0; k < 8; ++k) acc[k] = 0.f;

    seg_pipe<false>(mev, rp_m[row], rp_m[row + 1], e_in, li, acc, nullptr);

    const u32* ep_ = (const u32*)&eq;
    float res[8];
#pragma unroll
    for (int k = 0; k < 4; ++k) {
        res[2 * k]     = acc[2 * k]     + ALPHA_C * lo_bf(ep_[k]);
        res[2 * k + 1] = acc[2 * k + 1] + ALPHA_C * hi_bf(ep_[k]);
    }

    if (FINAL) {
        u4v q0 = __builtin_nontemporal_load((const u4v*)(e0 + (size_t)row * DIM) + li);
        u4v q1 = __builtin_nontemporal_load((const u4v*)(e1 + (size_t)row * DIM) + li);
        float of[8];
#pragma unroll
        for (int k = 0; k < 4; ++k) {
            float lo = res[2 * k]     + lo_bf(ep_[k]) + lo_bf(q0[k]) + lo_bf(q1[k]);
            float hi = res[2 * k + 1] + hi_bf(ep_[k]) + hi_bf(q0[k]) + hi_bf(q1[k]);
            of[2 * k]     = 0.25f * lo;
            of[2 * k + 1] = 0.25f * hi;
        }
        f4v o0, o1;
        o0.x = of[0]; o0.y = of[1]; o0.z = of[2]; o0.w = of[3];
        o1.x = of[4]; o1.y = of[5]; o1.z = of[6]; o1.w = of[7];
        f4v* sp = (f4v*)(out + (size_t)row * DIM) + li * 2;
        __builtin_nontemporal_store(o0, sp);
        __builtin_nontemporal_store(o1, sp + 1);
    } else {
        u32 o[4];
#pragma unroll
        for (int k = 0; k < 4; ++k)
            o[k] = (u32)f2bf(res[2 * k]) | ((u32)f2bf(res[2 * k + 1]) << 16);
        *((uint4*)(e_out + (size_t)row * DIM) + li) = *(uint4*)o;
    }
}

// ---------------------------------------------------------------------------
extern "C" void kernel_launch(void* const* d_in, const int* in_sizes, int n_in,
                              void* d_out, int out_size, void* d_ws, size_t ws_size,
                              hipStream_t stream) {
    const float* user_emb = (const float*)d_in[0];
    const float* item_emb = (const float*)d_in[1];
    const float* theta    = (const float*)d_in[2];
    const int*   pos_row  = (const int*)d_in[3];
    const int*   pos_col  = (const int*)d_in[4];
    const float* pos_val  = (const float*)d_in[5];
    const int*   neg_row  = (const int*)d_in[6];
    const int*   neg_col  = (const int*)d_in[7];
    const float* neg_val  = (const float*)d_in[8];
    const int*   p_row    = (const int*)d_in[9];
    const int*   p_col    = (const int*)d_in[10];
    const float* p_counts = (const float*)d_in[11];
    const int E_pos  = in_sizes[3];
    const int E_neg  = in_sizes[6];
    const int E_path = in_sizes[9];

    // bump allocator over d_ws (256B aligned chunks)
    char* wsb = (char*)d_ws;
    size_t off = 0;
    auto alloc = [&](size_t bytes) -> void* {
        void* p = wsb + off;
        off = (off + bytes + 255) & ~(size_t)255;
        return p;
    };
    i2v*   pev     = (i2v*)alloc((size_t)E_path * sizeof(i2v));
    int*   rp_pos  = (int*)alloc((size_t)(NUM_NODES + 1) * sizeof(int));
    int*   rp_neg  = (int*)alloc((size_t)(NUM_NODES + 1) * sizeof(int));
    int*   rp_path = (int*)alloc((size_t)(NUM_NODES + 1) * sizeof(int));
    int*   rp_m    = (int*)alloc((size_t)(NUM_NODES + 1) * sizeof(int));
    i2v*   mev     = (i2v*)alloc((size_t)(E_pos + E_neg) * sizeof(i2v));
    u16*   emb16   = (u16*)alloc((size_t)NUM_NODES * DIM * sizeof(u16));
    u16*   e0      = (u16*)alloc((size_t)NUM_NODES * DIM * sizeof(u16));
    u16*   e1      = (u16*)alloc((size_t)NUM_NODES * DIM * sizeof(u16));
    u16*   e2      = emb16;   // emb16 is dead after k_path; reuse for e2
    float* outp    = (float*)d_out;

    // fused prep: expv_pack | cvt | row_ptr4
    int nb_expv = (E_path + 255) / 256;
    int nb_cvt  = ((NUM_NODES * DIM) / 4 + 255) / 256;
    int nb_rp   = (4 * (NUM_NODES + 1) + 255) / 256;
    k_prep<<<nb_expv + nb_cvt + nb_rp, 256, 0, stream>>>(
        p_counts, theta, p_col, pev, E_path,
        user_emb, item_emb, emb16,
        pos_row, E_pos, rp_pos, neg_row, E_neg, rp_neg, p_row, E_path, rp_path,
        rp_m, nb_expv, nb_cvt);

    int E_tot = E_pos + E_neg;
    k_merge_e<<<(E_tot + 255) / 256, 256, 0, stream>>>(
        pos_row, pos_col, pos_val, neg_row, neg_col, neg_val,
        rp_pos, rp_neg, mev, E_pos, E_tot);

    // one 8-lane group per row: 32 rows per 256-thread block
    int row_blocks = (NUM_NODES + 31) / 32;  // 3750

    k_path<<<row_blocks, 256, 0, stream>>>(emb16, pev, rp_path, e0);
    k_layer_t<0><<<row_blocks, 256, 0, stream>>>(e0, e1, nullptr, nullptr, nullptr,
                                                 rp_m, mev);
    k_layer_t<0><<<row_blocks, 256, 0, stream>>>(e1, e2, nullptr, nullptr, nullptr,
                                                 rp_m, mev);
    k_layer_t<1><<<row_blocks, 256, 0, stream>>>(e2, nullptr, e0, e1, outp,
                                                 rp_m, mev);
}

// Round 7
// 455.695 us; speedup vs baseline: 3.1451x; 1.0538x over previous
//
#include <hip/hip_runtime.h>

#define NUM_USERS 80000
#define NUM_ITEMS 40000
#define NUM_NODES 120000
#define DIM 64
#define ALPHA_C 0.8f

typedef unsigned short u16;
typedef unsigned int u32;
typedef float f4v __attribute__((ext_vector_type(4)));

// fp32 -> bf16 round-nearest-even
__device__ __forceinline__ u16 f2bf(float f) {
    union { float f; u32 i; } v;
    v.f = f;
    u32 i = v.i;
    u32 r = (i + 0x7FFFu + ((i >> 16) & 1u)) >> 16;
    return (u16)r;
}
__device__ __forceinline__ float lo_bf(u32 u) { return __uint_as_float(u << 16); }
__device__ __forceinline__ float hi_bf(u32 u) { return __uint_as_float(u & 0xffff0000u); }

// accumulate 8 bf16 (packed in uint4) * v into acc[8]
__device__ __forceinline__ void acc8(float* __restrict__ acc, float v, uint4 q) {
    const u32* p = (const u32*)&q;
#pragma unroll
    for (int k = 0; k < 4; ++k) {
        u32 u = p[k];
        acc[2 * k]     = fmaf(v, lo_bf(u), acc[2 * k]);
        acc[2 * k + 1] = fmaf(v, hi_bf(u), acc[2 * k + 1]);
    }
}

__device__ __forceinline__ uint4 ldrow(const u16* __restrict__ x, int c, int li) {
    return *((const uint4*)(x + (size_t)c * DIM) + li);
}

// ---------------------------------------------------------------------------
// R0's proven walk: software-pipelined segment gather, depth-2.
// 8-lane group walks its whole segment; 2-stage prefetch of col/val +
// 1-stage prefetch of row gathers. Lane li owns elements [8*li, 8*li+8).
// Edge weights are multiplied by `scale` at use (folds pos/neg sign+alpha).
// If SUMV, also accumulates the UNSCALED sum of val into *vsum.
// LESSONS BAKED IN (R1-R6 arc):
//  - R2: edge loads must be normal cached loads (group touches each 64B
//    line 4x; nt evict-first cost +82MB FETCH, +33% time).
//  - R5: natural row order; degree-sorting trades locality for lane
//    balance and loses (~-4%).
//  - R6: depth-3 gathers are neutral-to-negative (per-CU miss concurrency
//    already saturated at ~14 waves/CU); depth-2 is the sweet spot.
//  - R0-R6: merged pos+neg edge stream saves 20us in layers but costs
//    ~35-40us in prep -> two-walk structure is net best.
// ---------------------------------------------------------------------------
template <bool SUMV>
__device__ __forceinline__ void seg_pipe_t(const int* __restrict__ col,
                                           const float* __restrict__ val,
                                           int start, int end,
                                           const u16* __restrict__ x,
                                           int li, float scale,
                                           float* __restrict__ acc,
                                           float* __restrict__ vsum) {
    int n = end - start;
    const int* cp = col + start;
    const float* vp = val + start;
    float s = 0.f;
    int np = n >> 1;
    if (np >= 2) {
        float va0 = vp[0], va1 = vp[1];
        int   cb0 = cp[2], cb1 = cp[3];
        float vb0 = vp[2], vb1 = vp[3];
        uint4 xa0 = ldrow(x, cp[0], li);
        uint4 xa1 = ldrow(x, cp[1], li);
        for (int p = 2; p < np; ++p) {
            int   cc0 = cp[2 * p],     cc1 = cp[2 * p + 1];
            float vc0 = vp[2 * p],     vc1 = vp[2 * p + 1];
            uint4 xb0 = ldrow(x, cb0, li);
            uint4 xb1 = ldrow(x, cb1, li);
            acc8(acc, va0 * scale, xa0);
            acc8(acc, va1 * scale, xa1);
            if (SUMV) s += va0 + va1;
            va0 = vb0; va1 = vb1; xa0 = xb0; xa1 = xb1;
            cb0 = cc0; cb1 = cc1; vb0 = vc0; vb1 = vc1;
        }
        uint4 xb0 = ldrow(x, cb0, li);
        uint4 xb1 = ldrow(x, cb1, li);
        acc8(acc, va0 * scale, xa0);
        acc8(acc, va1 * scale, xa1);
        acc8(acc, vb0 * scale, xb0);
        acc8(acc, vb1 * scale, xb1);
        if (SUMV) s += va0 + va1 + vb0 + vb1;
        if (n & 1) {
            float v = vp[n - 1];
            uint4 xq = ldrow(x, cp[n - 1], li);
            acc8(acc, v * scale, xq);
            if (SUMV) s += v;
        }
    } else {
        for (int e = 0; e < n; ++e) {
            float v = vp[e];
            uint4 xq = ldrow(x, cp[e], li);
            acc8(acc, v * scale, xq);
            if (SUMV) s += v;
        }
    }
    if (SUMV) *vsum = s;
}

__device__ __forceinline__ int lower_bound_v(const int* __restrict__ rows,
                                             int nnz, int r) {
    int lo = 0, hi = nnz;
    while (lo < hi) {
        int mid = (lo + hi) >> 1;
        if (rows[mid] < r) lo = mid + 1; else hi = mid;
    }
    return lo;
}

// ---------------------------------------------------------------------------
// K1 (fused prep) -- three independent jobs partitioned by blockIdx range:
//   [0, nb_expv)         : exp_v[i] = exp(dot(p_counts[i,0:6], softmax(theta)))
//   [nb_expv, +nb_cvt)   : user||item fp32 -> bf16 table
//   [.., end)            : 3 CSR row_ptr arrays (pos, neg, path)
// The softmax is recomputed per thread with the exact expression chain of
// the original two-kernel version -> bitwise-same exp_v.
// ---------------------------------------------------------------------------
__global__ void k_prep(const float* __restrict__ p_counts,
                       const float* __restrict__ theta,
                       float* __restrict__ exp_v, int E_path,
                       const float* __restrict__ user_emb,
                       const float* __restrict__ item_emb,
                       u16* __restrict__ emb16,
                       const int* __restrict__ rows_a, int nnz_a, int* __restrict__ pa,
                       const int* __restrict__ rows_b, int nnz_b, int* __restrict__ pb,
                       const int* __restrict__ rows_c, int nnz_c, int* __restrict__ pc,
                       int nb_expv, int nb_cvt) {
    int b = blockIdx.x;
    int tid = threadIdx.x;
    if (b < nb_expv) {
        int i = b * 256 + tid;
        if (i >= E_path) return;
        float m = -1e30f;
        for (int k = 0; k < 6; ++k) m = fmaxf(m, theta[k]);
        float e[6];
        float s = 0.f;
        for (int k = 0; k < 6; ++k) { e[k] = expf(theta[k] - m); s += e[k]; }
        float w0 = e[0] / s, w1 = e[1] / s, w2 = e[2] / s,
              w3 = e[3] / s, w4 = e[4] / s, w5 = e[5] / s;
        const float* c = p_counts + (size_t)i * 6;
        float v = c[0] * w0 + c[1] * w1 + c[2] * w2 +
                  c[3] * w3 + c[4] * w4 + c[5] * w5;
        exp_v[i] = expf(v);
    } else if (b < nb_expv + nb_cvt) {
        int i = (b - nb_expv) * 256 + tid;
        size_t f = (size_t)i * 4;
        const size_t UTOT = (size_t)NUM_USERS * DIM;
        const size_t TOT = (size_t)NUM_NODES * DIM;
        if (f >= TOT) return;
        f4v v = (f < UTOT)
            ? __builtin_nontemporal_load((const f4v*)(user_emb + f))
            : __builtin_nontemporal_load((const f4v*)(item_emb + (f - UTOT)));
        ushort4 o;
        o.x = f2bf(v.x); o.y = f2bf(v.y); o.z = f2bf(v.z); o.w = f2bf(v.w);
        *(ushort4*)(emb16 + f) = o;   // normal store: k_path gathers this next
    } else {
        int t = (b - nb_expv - nb_cvt) * 256 + tid;
        int which = t / (NUM_NODES + 1);
        int r = t - which * (NUM_NODES + 1);
        if (which == 0) pa[r] = lower_bound_v(rows_a, nnz_a, r);
        else if (which == 1) pb[r] = lower_bound_v(rows_b, nnz_b, r);
        else if (which == 2) pc[r] = lower_bound_v(rows_c, nnz_c, r);
    }
}

// ---------------------------------------------------------------------------
// K2: path SpMM with fused row-softmax. One 8-lane group per row.
//     acc = sum_e exp_v[e]*x[col[e]]; denominator accumulated in-walk;
//     e0 = acc / (sum + 1e-12). bf16 out only.
// ---------------------------------------------------------------------------
__global__ void k_path(const u16* __restrict__ emb16,
                       const float* __restrict__ exp_v,
                       const int* __restrict__ rp,
                       const int* __restrict__ cols,
                       u16* __restrict__ e0) {
    int t = blockIdx.x * blockDim.x + threadIdx.x;
    int row = t >> 3;            // one 8-lane group per row
    if (row >= NUM_NODES) return;
    int li = threadIdx.x & 7;
    int start = rp[row], end = rp[row + 1];

    float acc[8];
#pragma unroll
    for (int k = 0; k < 8; ++k) acc[k] = 0.f;
    float s = 0.f;

    seg_pipe_t<true>(cols, exp_v, start, end, emb16, li, 1.0f, acc, &s);

    float inv = 1.0f / (s + 1e-12f);
    u32 o[4];
#pragma unroll
    for (int k = 0; k < 4; ++k)
        o[k] = (u32)f2bf(acc[2 * k] * inv) | ((u32)f2bf(acc[2 * k + 1] * inv) << 16);
    *((uint4*)(e0 + (size_t)row * DIM) + li) = *(uint4*)o;
}

// ---------------------------------------------------------------------------
// K3: one propagation layer. One 8-lane group per row. Single accumulator:
//     acc = sum_pos val*x  - ALPHA * sum_neg val*x ; res = acc + ALPHA*e_in
//     FINAL=0: write res (bf16) to e_out.
//     FINAL=1: out = 0.25*(e0 + e1 + e_in + res)  (fp32, straight to d_out)
// ---------------------------------------------------------------------------
template <int FINAL>
__global__ void k_layer_t(const u16* __restrict__ e_in,
                          u16* __restrict__ e_out,
                          const u16* __restrict__ e0,
                          const u16* __restrict__ e1,
                          float* __restrict__ out,
                          const int* __restrict__ rp_p,
                          const int* __restrict__ col_p,
                          const float* __restrict__ val_p,
                          const int* __restrict__ rp_n,
                          const int* __restrict__ col_n,
                          const float* __restrict__ val_n) {
    int t = blockIdx.x * blockDim.x + threadIdx.x;
    int row = t >> 3;            // one 8-lane group per row
    if (row >= NUM_NODES) return;
    int li = threadIdx.x & 7;

    uint4 eq = *((const uint4*)(e_in + (size_t)row * DIM) + li);  // overlap with walk

    float acc[8];
#pragma unroll
    for (int k = 0; k < 8; ++k) acc[k] = 0.f;

    seg_pipe_t<false>(col_p, val_p, rp_p[row], rp_p[row + 1], e_in, li, 1.0f,
                      acc, nullptr);
    seg_pipe_t<false>(col_n, val_n, rp_n[row], rp_n[row + 1], e_in, li, -ALPHA_C,
                      acc, nullptr);

    const u32* ep = (const u32*)&eq;
    float res[8];
#pragma unroll
    for (int k = 0; k < 4; ++k) {
        res[2 * k]     = acc[2 * k]     + ALPHA_C * lo_bf(ep[k]);
        res[2 * k + 1] = acc[2 * k + 1] + ALPHA_C * hi_bf(ep[k]);
    }

    if (FINAL) {
        uint4 q0 = *((const uint4*)(e0 + (size_t)row * DIM) + li);
        uint4 q1 = *((const uint4*)(e1 + (size_t)row * DIM) + li);
        const u32* p0 = (const u32*)&q0;
        const u32* p1 = (const u32*)&q1;
        float4 o0, o1;
        float* oo[2] = { (float*)&o0, (float*)&o1 };
#pragma unroll
        for (int k = 0; k < 4; ++k) {
            float lo = res[2 * k]     + lo_bf(ep[k]) + lo_bf(p0[k]) + lo_bf(p1[k]);
            float hi = res[2 * k + 1] + hi_bf(ep[k]) + hi_bf(p0[k]) + hi_bf(p1[k]);
            oo[k >> 1][(k & 1) * 2]     = 0.25f * lo;
            oo[k >> 1][(k & 1) * 2 + 1] = 0.25f * hi;
        }
        float4* sp = (float4*)(out + (size_t)row * DIM) + li * 2;
        sp[0] = o0;
        sp[1] = o1;
    } else {
        u32 o[4];
#pragma unroll
        for (int k = 0; k < 4; ++k)
            o[k] = (u32)f2bf(res[2 * k]) | ((u32)f2bf(res[2 * k + 1]) << 16);
        *((uint4*)(e_out + (size_t)row * DIM) + li) = *(uint4*)o;
    }
}

// ---------------------------------------------------------------------------
extern "C" void kernel_launch(void* const* d_in, const int* in_sizes, int n_in,
                              void* d_out, int out_size, void* d_ws, size_t ws_size,
                              hipStream_t stream) {
    const float* user_emb = (const float*)d_in[0];
    const float* item_emb = (const float*)d_in[1];
    const float* theta    = (const float*)d_in[2];
    const int*   pos_row  = (const int*)d_in[3];
    const int*   pos_col  = (const int*)d_in[4];
    const float* pos_val  = (const float*)d_in[5];
    const int*   neg_row  = (const int*)d_in[6];
    const int*   neg_col  = (const int*)d_in[7];
    const float* neg_val  = (const float*)d_in[8];
    const int*   p_row    = (const int*)d_in[9];
    const int*   p_col    = (const int*)d_in[10];
    const float* p_counts = (const float*)d_in[11];
    const int E_pos  = in_sizes[3];
    const int E_neg  = in_sizes[6];
    const int E_path = in_sizes[9];

    // bump allocator over d_ws (256B aligned chunks)
    char* wsb = (char*)d_ws;
    size_t off = 0;
    auto alloc = [&](size_t bytes) -> void* {
        void* p = wsb + off;
        off = (off + bytes + 255) & ~(size_t)255;
        return p;
    };
    float* exp_v   = (float*)alloc((size_t)E_path * sizeof(float));
    int*   rp_pos  = (int*)alloc((size_t)(NUM_NODES + 1) * sizeof(int));
    int*   rp_neg  = (int*)alloc((size_t)(NUM_NODES + 1) * sizeof(int));
    int*   rp_path = (int*)alloc((size_t)(NUM_NODES + 1) * sizeof(int));
    u16*   emb16   = (u16*)alloc((size_t)NUM_NODES * DIM * sizeof(u16));
    u16*   e0      = (u16*)alloc((size_t)NUM_NODES * DIM * sizeof(u16));
    u16*   e1      = (u16*)alloc((size_t)NUM_NODES * DIM * sizeof(u16));
    u16*   e2      = emb16;   // emb16 is dead after k_path; reuse for e2
    float* outp    = (float*)d_out;

    // fused prep: expv (softmax inlined) | cvt | row_ptr3
    int nb_expv = (E_path + 255) / 256;
    int nb_cvt  = ((NUM_NODES * DIM) / 4 + 255) / 256;
    int nb_rp   = (3 * (NUM_NODES + 1) + 255) / 256;
    k_prep<<<nb_expv + nb_cvt + nb_rp, 256, 0, stream>>>(
        p_counts, theta, exp_v, E_path,
        user_emb, item_emb, emb16,
        pos_row, E_pos, rp_pos, neg_row, E_neg, rp_neg, p_row, E_path, rp_path,
        nb_expv, nb_cvt);

    // one 8-lane group per row: 32 rows per 256-thread block
    int row_blocks = (NUM_NODES + 31) / 32;  // 3750

    k_path<<<row_blocks, 256, 0, stream>>>(emb16, exp_v, rp_path, p_col, e0);
    k_layer_t<0><<<row_blocks, 256, 0, stream>>>(e0, e1, nullptr, nullptr, nullptr,
                                                 rp_pos, pos_col, pos_val,
                                                 rp_neg, neg_col, neg_val);
    k_layer_t<0><<<row_blocks, 256, 0, stream>>>(e1, e2, nullptr, nullptr, nullptr,
                                                 rp_pos, pos_col, pos_val,
                                                 rp_neg, neg_col, neg_val);
    k_layer_t<1><<<row_blocks, 256, 0, stream>>>(e2, nullptr, e0, e1, outp,
                                                 rp_pos, pos_col, pos_val,
                                                 rp_neg, neg_col, neg_val);
}